// Round 18
// baseline (193.399 us; speedup 1.0000x reference)
//
#include <hip/hip_runtime.h>
#include <hip/hip_bf16.h>
#include <hip/hip_fp16.h>

// Pipeline (pull-mode GCN, fp16-staged gather operands, line-dense CSR build,
// dot2 fused layer-GEMMs; gather/GEMM and prep/hist deliberately SEPARATE):
//   prep  : x_h = (half)relu(x); count[dst]++        (wide grid, 1 elem/thread)
//   histA : chunk histogram over dst -> histT         (LDS atomics only)
//   CSR   : scanA/scanB/scanC -> rowptr,dinv; scanP -> scatterB(4B pairs) -> fillC
//   z1h   = (half)Agg(x_h)           [n,128]   gather1 (wave/node, 8x unroll)
//   h2h   = (half)(relu(z1@W1+b1) @ W2)  [n,64]  fused_gemm (all-fp16 LDS, fp32 accum)
//   out   = softmax(Agg(h2h) + b2)   [n,64]    gather2+softmax fused
// Agg(v)[d] = v[d]*dinv[d]^2 + sum_{s in N(d)} v[s]*dinv[s]*dinv[d], dinv = rsqrt(deg+1)
//
// R17 lesson (mirror of R16's): folding the 800K random global count atomics
// into the 196-block CHUNK kernel starved them of TLP (prep 45us @ 6% occ,
// VALUBusy 1.3%). Split back: wide prep (R15-proven) + chunked LDS-only histA.
// All kernels verbatim from previously-passed rounds; absmax unchanged.

#define SCAN_B 256
#define CHUNK  4096      // edges per block in histA/scatterB -> nblocks<=256 for E<=1M
#define BSHIFT 7         // 128-node buckets
#define NBMAX  512       // max buckets -> n <= 65536 (also makes src fit in 16 bits)
#define XLH_LD 136       // xlh row stride in halfs: 272B (16B aligned, banks +4/row)

typedef _Float16 h2v __attribute__((ext_vector_type(2)));
union WU4 { uint4 u; h2v h[4]; };
union HO4 { uint2 u; _Float16 h[4]; };

__device__ __forceinline__ float fdot2(h2v a, h2v b, float c) {
#if __has_builtin(__builtin_amdgcn_fdot2)
    return __builtin_amdgcn_fdot2(a, b, c, false);
#else
    return fmaf((float)a[1], (float)b[1], fmaf((float)a[0], (float)b[0], c));
#endif
}

// ---------------- prep: x -> relu -> fp16, and count[dst]++ (wide, 1 elem/thread) ----------------

__global__ __launch_bounds__(256) void prep_kernel(
    const float* __restrict__ x, __half* __restrict__ xh, int total8,
    const int* __restrict__ dst, int* __restrict__ count, int E)
{
    const int i = blockIdx.x * blockDim.x + threadIdx.x;
    if (i < total8) {
        const float4 v0 = *(const float4*)&x[(size_t)i * 8];
        const float4 v1 = *(const float4*)&x[(size_t)i * 8 + 4];
        union { __half2 h[4]; float4 f; } u;
        u.h[0] = __floats2half2_rn(fmaxf(v0.x, 0.f), fmaxf(v0.y, 0.f));
        u.h[1] = __floats2half2_rn(fmaxf(v0.z, 0.f), fmaxf(v0.w, 0.f));
        u.h[2] = __floats2half2_rn(fmaxf(v1.x, 0.f), fmaxf(v1.y, 0.f));
        u.h[3] = __floats2half2_rn(fmaxf(v1.z, 0.f), fmaxf(v1.w, 0.f));
        *(float4*)&xh[(size_t)i * 8] = u.f;
    }
    if (i < E) atomicAdd(&count[dst[i]], 1);
}

// ---------------- histA: per-chunk histogram, TRANSPOSED store histT[bucket][chunk] ----------------

__global__ __launch_bounds__(256) void histA_kernel(
    const int* __restrict__ dst, int* __restrict__ histT, int E, int NB, int nblocks)
{
    __shared__ int h[NBMAX];
    const int tid = threadIdx.x;
    for (int i = tid; i < NB; i += 256) h[i] = 0;
    __syncthreads();
    const int base = blockIdx.x * CHUNK;
    #pragma unroll
    for (int i = 0; i < CHUNK / 256; ++i) {
        const int e = base + i * 256 + tid;
        if (e < E) atomicAdd(&h[dst[e] >> BSHIFT], 1);
    }
    __syncthreads();
    for (int i = tid; i < NB; i += 256) histT[i * nblocks + blockIdx.x] = h[i];
}

// ---------------- zero ----------------

__global__ void zero_kernel(int* __restrict__ p, int m) {
    int i = blockIdx.x * blockDim.x + threadIdx.x;
    if (i < m) p[i] = 0;
}

// ---------------- hierarchical exclusive scan of count -> rowptr ----------------

__global__ __launch_bounds__(SCAN_B) void scanA_kernel(
    const int* __restrict__ count, int* __restrict__ rowptr,
    int* __restrict__ bsum, int n)
{
    __shared__ int s[SCAN_B];
    const int tid = threadIdx.x;
    const int gid = blockIdx.x * SCAN_B + tid;
    const int v = (gid < n) ? count[gid] : 0;
    s[tid] = v;
    __syncthreads();
    for (int off = 1; off < SCAN_B; off <<= 1) {
        const int t = (tid >= off) ? s[tid - off] : 0;
        __syncthreads();
        s[tid] += t;
        __syncthreads();
    }
    if (gid < n) rowptr[gid] = s[tid] - v;            // exclusive
    if (tid == SCAN_B - 1) bsum[blockIdx.x] = s[tid]; // block total
}

__global__ __launch_bounds__(SCAN_B) void scanB_kernel(
    const int* __restrict__ bsum, int* __restrict__ boff, int nb)
{
    __shared__ int s[SCAN_B];
    const int tid = threadIdx.x;
    const int v = (tid < nb) ? bsum[tid] : 0;
    s[tid] = v;
    __syncthreads();
    for (int off = 1; off < SCAN_B; off <<= 1) {
        const int t = (tid >= off) ? s[tid - off] : 0;
        __syncthreads();
        s[tid] += t;
        __syncthreads();
    }
    if (tid < nb) boff[tid] = s[tid] - v;
}

// rowptr += block offset; dinv = rsqrt(count+1); rowptr[n] = E
__global__ void scanC_kernel(int* __restrict__ rowptr, const int* __restrict__ boff,
                             const int* __restrict__ count,
                             float* __restrict__ dinv, int n, int E)
{
    const int gid = blockIdx.x * blockDim.x + threadIdx.x;
    if (gid < n) {
        rowptr[gid] = rowptr[gid] + boff[gid >> 8];   // scanA block size = 256
        dinv[gid] = rsqrtf((float)count[gid] + 1.0f);
    }
    if (gid == 0) rowptr[n] = E;
}

// ---------------- scanP: parallel per-bucket exclusive scan over chunks ----------------

__global__ __launch_bounds__(256) void scanP_kernel(
    const int* __restrict__ histT, const int* __restrict__ rowptr,
    int* __restrict__ boff2T, int nblocks)
{
    __shared__ int s[256];
    const int b = blockIdx.x;
    const int tid = threadIdx.x;
    const int v = (tid < nblocks) ? histT[b * nblocks + tid] : 0;
    s[tid] = v;
    __syncthreads();
    for (int off = 1; off < 256; off <<= 1) {
        const int t = (tid >= off) ? s[tid - off] : 0;
        __syncthreads();
        s[tid] += t;
        __syncthreads();
    }
    if (tid < nblocks)
        boff2T[b * nblocks + tid] = rowptr[b << BSHIFT] + s[tid] - v;
}

// ---------------- scatterB: edges -> packed 4B pairs, bucket-sorted dense runs ----------------
// pack = (dlocal << 16) | src   (src < 65536 since n <= NBMAX<<BSHIFT = 65536)

__global__ __launch_bounds__(256) void scatterB_kernel(
    const int* __restrict__ src, const int* __restrict__ dst,
    const int* __restrict__ boff2T, unsigned int* __restrict__ pairs,
    int E, int NB, int nblocks)
{
    __shared__ int lcnt[NBMAX];
    __shared__ int lbase[NBMAX];
    const int tid = threadIdx.x;
    for (int i = tid; i < NB; i += 256) {
        lcnt[i] = 0;
        lbase[i] = boff2T[i * nblocks + blockIdx.x];
    }
    __syncthreads();
    const int base = blockIdx.x * CHUNK;
    #pragma unroll
    for (int i = 0; i < CHUNK / 256; ++i) {
        const int e = base + i * 256 + tid;
        if (e < E) {
            const int d = dst[e];
            const int b = d >> BSHIFT;
            const int r = atomicAdd(&lcnt[b], 1);
            pairs[lbase[b] + r] =
                ((unsigned int)(d & ((1 << BSHIFT) - 1)) << 16) | (unsigned int)src[e];
        }
    }
}

// ---------------- fillC: one block per 128-node bucket, LDS cursors, local col writes ----------------

__global__ __launch_bounds__(256) void fillC_kernel(
    const unsigned int* __restrict__ pairs, const int* __restrict__ rowptr,
    int* __restrict__ col, int n)
{
    __shared__ int curs[128];
    const int node0 = blockIdx.x << BSHIFT;
    const int tid = threadIdx.x;
    if (tid < 128) {
        const int node = node0 + tid;
        if (node < n) curs[tid] = rowptr[node];
    }
    __syncthreads();
    const int lo = rowptr[node0];
    const int hiN = (node0 + 128 < n) ? node0 + 128 : n;
    const int hi = rowptr[hiN];                       // rowptr[n] = E sentinel
    for (int t = lo + tid; t < hi; t += 256) {
        const unsigned int p = pairs[t];
        const int pos = atomicAdd(&curs[p >> 16], 1);
        col[pos] = (int)(p & 0xFFFFu);
    }
}

// ---------------- gather1: z1h[d] = (half)Agg(x_h)[d], F=128 (wave/node, 8x unroll) ----------------

__global__ __launch_bounds__(256) void gather1_kernel(
    const __half* __restrict__ xh, const int* __restrict__ rowptr,
    const int* __restrict__ col, const float* __restrict__ dinv,
    __half* __restrict__ z1h, int n)
{
    const int wid = blockIdx.x * 4 + (threadIdx.x >> 6);
    if (wid >= n) return;
    const int lane = threadIdx.x & 63;
    const float dd = dinv[wid];
    const size_t selfoff = (size_t)wid * 128 + lane * 2;
    const float2 sv = __half22float2(*(const __half2*)&xh[selfoff]);
    float2 a0, a1, a2, a3;
    a0.x = sv.x * dd * dd;
    a0.y = sv.y * dd * dd;
    a1 = make_float2(0.f, 0.f);
    a2 = make_float2(0.f, 0.f);
    a3 = make_float2(0.f, 0.f);
    const int jb = rowptr[wid];
    const int je = rowptr[wid + 1];
    int j = jb;
    for (; j + 7 < je; j += 8) {
        const int s0 = col[j + 0];
        const int s1 = col[j + 1];
        const int s2 = col[j + 2];
        const int s3 = col[j + 3];
        const int s4 = col[j + 4];
        const int s5 = col[j + 5];
        const int s6 = col[j + 6];
        const int s7 = col[j + 7];
        const float n0 = dinv[s0] * dd;
        const float n1 = dinv[s1] * dd;
        const float n2 = dinv[s2] * dd;
        const float n3 = dinv[s3] * dd;
        const float n4 = dinv[s4] * dd;
        const float n5 = dinv[s5] * dd;
        const float n6 = dinv[s6] * dd;
        const float n7 = dinv[s7] * dd;
        const float2 v0 = __half22float2(*(const __half2*)&xh[(size_t)s0 * 128 + lane * 2]);
        const float2 v1 = __half22float2(*(const __half2*)&xh[(size_t)s1 * 128 + lane * 2]);
        const float2 v2 = __half22float2(*(const __half2*)&xh[(size_t)s2 * 128 + lane * 2]);
        const float2 v3 = __half22float2(*(const __half2*)&xh[(size_t)s3 * 128 + lane * 2]);
        const float2 v4 = __half22float2(*(const __half2*)&xh[(size_t)s4 * 128 + lane * 2]);
        const float2 v5 = __half22float2(*(const __half2*)&xh[(size_t)s5 * 128 + lane * 2]);
        const float2 v6 = __half22float2(*(const __half2*)&xh[(size_t)s6 * 128 + lane * 2]);
        const float2 v7 = __half22float2(*(const __half2*)&xh[(size_t)s7 * 128 + lane * 2]);
        a0.x = fmaf(v0.x, n0, a0.x);
        a0.y = fmaf(v0.y, n0, a0.y);
        a1.x = fmaf(v1.x, n1, a1.x);
        a1.y = fmaf(v1.y, n1, a1.y);
        a2.x = fmaf(v2.x, n2, a2.x);
        a2.y = fmaf(v2.y, n2, a2.y);
        a3.x = fmaf(v3.x, n3, a3.x);
        a3.y = fmaf(v3.y, n3, a3.y);
        a0.x = fmaf(v4.x, n4, a0.x);
        a0.y = fmaf(v4.y, n4, a0.y);
        a1.x = fmaf(v5.x, n5, a1.x);
        a1.y = fmaf(v5.y, n5, a1.y);
        a2.x = fmaf(v6.x, n6, a2.x);
        a2.y = fmaf(v6.y, n6, a2.y);
        a3.x = fmaf(v7.x, n7, a3.x);
        a3.y = fmaf(v7.y, n7, a3.y);
    }
    for (; j < je; ++j) {
        const int s = col[j];
        const float nrm = dinv[s] * dd;
        const float2 v = __half22float2(*(const __half2*)&xh[(size_t)s * 128 + lane * 2]);
        a0.x = fmaf(v.x, nrm, a0.x);
        a0.y = fmaf(v.y, nrm, a0.y);
    }
    const float fx = (a0.x + a1.x) + (a2.x + a3.x);
    const float fy = (a0.y + a1.y) + (a2.y + a3.y);
    *(__half2*)&z1h[selfoff] = __floats2half2_rn(fx, fy);
}

// ---------------- fused_gemm: h2h = (half)(relu(z1@W1+b1) @ W2), fp16 dot2 ----------------
// 512 thr, 64-row block. LDS: Wu (k-pair-packed half2; W1p 32KB / W2p 16KB time-shared)
// + xlh[64][136] fp16 17KB = 50176B -> 3 blocks/CU. fp32 accumulation via dot2.

__global__ __launch_bounds__(512) void fused_gemm_kernel(
    const __half* __restrict__ z1h, const float* __restrict__ W1,
    const float* __restrict__ b1, const float* __restrict__ W2,
    __half* __restrict__ h2h, int n)
{
    __shared__ __align__(16) h2v Wu[64 * 128];          // 32 KB: W1p then W2p
    __shared__ __align__(16) _Float16 xlh[64][XLH_LD];  // 17 KB
    const int tid = threadIdx.x;

    const int colg = tid & 31;        // phase B: 32 col groups x 4 = 128 cols
    const int j0   = colg * 4;
    const int r0   = (tid >> 5) * 4;  // 16 row groups x 4 = 64 rows

    const float4 bbv = *(const float4*)&b1[j0];  // bias for this thread's cols (L2-hot)

    // ---- phase A: stage W1 -> k-pair-packed fp16; 64 z1h rows ----
    {
        const float4* W4 = (const float4*)W1;   // W1[k][col], 32 float4 per k-row
        #pragma unroll
        for (int i = 0; i < 4; ++i) {
            const int idx = tid + i * 512;      // [0,2048): kp = idx>>5, c4 = idx&31
            const int kp = idx >> 5;
            const int c4 = idx & 31;
            const float4 f0 = W4[(2 * kp) * 32 + c4];
            const float4 f1 = W4[(2 * kp + 1) * 32 + c4];
            WU4 w;
            w.h[0] = h2v{(_Float16)f0.x, (_Float16)f1.x};
            w.h[1] = h2v{(_Float16)f0.y, (_Float16)f1.y};
            w.h[2] = h2v{(_Float16)f0.z, (_Float16)f1.z};
            w.h[3] = h2v{(_Float16)f0.w, (_Float16)f1.w};
            *(uint4*)&Wu[kp * 128 + c4 * 4] = w.u;
        }
    }
    const int row0 = blockIdx.x * 64;
    #pragma unroll
    for (int t = 0; t < 2; ++t) {
        const int idx = tid + t * 512;          // [0,1024): rr = idx>>4, c8 = idx&15
        const int rr = idx >> 4;
        const int c8 = idx & 15;
        const int grow = row0 + rr;
        float4 v = make_float4(0.f, 0.f, 0.f, 0.f);
        if (grow < n) v = *(const float4*)&z1h[(size_t)grow * 128 + c8 * 8];
        *(float4*)&xlh[rr][c8 * 8] = v;         // 8 halfs, 16B aligned (stride 272B)
    }
    __syncthreads();

    // ---- phase B: x1 = relu(z1 @ W1 + b1), 4 rows x 4 cols / thread, dot2 over k-pairs ----
    float c00 = 0.f, c01 = 0.f, c02 = 0.f, c03 = 0.f;
    float c10 = 0.f, c11 = 0.f, c12 = 0.f, c13 = 0.f;
    float c20 = 0.f, c21 = 0.f, c22 = 0.f, c23 = 0.f;
    float c30 = 0.f, c31 = 0.f, c32 = 0.f, c33 = 0.f;
    #pragma unroll 8
    for (int kp = 0; kp < 64; ++kp) {
        WU4 w; w.u = *(const uint4*)&Wu[kp * 128 + j0];
        const h2v x0 = *(const h2v*)&xlh[r0 + 0][kp * 2];
        const h2v x1 = *(const h2v*)&xlh[r0 + 1][kp * 2];
        const h2v x2 = *(const h2v*)&xlh[r0 + 2][kp * 2];
        const h2v x3 = *(const h2v*)&xlh[r0 + 3][kp * 2];
        c00 = fdot2(x0, w.h[0], c00); c01 = fdot2(x0, w.h[1], c01);
        c02 = fdot2(x0, w.h[2], c02); c03 = fdot2(x0, w.h[3], c03);
        c10 = fdot2(x1, w.h[0], c10); c11 = fdot2(x1, w.h[1], c11);
        c12 = fdot2(x1, w.h[2], c12); c13 = fdot2(x1, w.h[3], c13);
        c20 = fdot2(x2, w.h[0], c20); c21 = fdot2(x2, w.h[1], c21);
        c22 = fdot2(x2, w.h[2], c22); c23 = fdot2(x2, w.h[3], c23);
        c30 = fdot2(x3, w.h[0], c30); c31 = fdot2(x3, w.h[1], c31);
        c32 = fdot2(x3, w.h[2], c32); c33 = fdot2(x3, w.h[3], c33);
    }
    __syncthreads();   // phase-B reads of xlh AND Wu complete before overwrite

    // ---- phase C: write x1 (fp16) into xlh; stage W2 -> k-pair-packed fp16 into Wu ----
    {
        HO4 o0, o1, o2, o3;
        o0.h[0] = (_Float16)fmaxf(c00 + bbv.x, 0.f);
        o0.h[1] = (_Float16)fmaxf(c01 + bbv.y, 0.f);
        o0.h[2] = (_Float16)fmaxf(c02 + bbv.z, 0.f);
        o0.h[3] = (_Float16)fmaxf(c03 + bbv.w, 0.f);
        o1.h[0] = (_Float16)fmaxf(c10 + bbv.x, 0.f);
        o1.h[1] = (_Float16)fmaxf(c11 + bbv.y, 0.f);
        o1.h[2] = (_Float16)fmaxf(c12 + bbv.z, 0.f);
        o1.h[3] = (_Float16)fmaxf(c13 + bbv.w, 0.f);
        o2.h[0] = (_Float16)fmaxf(c20 + bbv.x, 0.f);
        o2.h[1] = (_Float16)fmaxf(c21 + bbv.y, 0.f);
        o2.h[2] = (_Float16)fmaxf(c22 + bbv.z, 0.f);
        o2.h[3] = (_Float16)fmaxf(c23 + bbv.w, 0.f);
        o3.h[0] = (_Float16)fmaxf(c30 + bbv.x, 0.f);
        o3.h[1] = (_Float16)fmaxf(c31 + bbv.y, 0.f);
        o3.h[2] = (_Float16)fmaxf(c32 + bbv.z, 0.f);
        o3.h[3] = (_Float16)fmaxf(c33 + bbv.w, 0.f);
        *(uint2*)&xlh[r0 + 0][j0] = o0.u;   // 8B writes, row stride 272B
        *(uint2*)&xlh[r0 + 1][j0] = o1.u;
        *(uint2*)&xlh[r0 + 2][j0] = o2.u;
        *(uint2*)&xlh[r0 + 3][j0] = o3.u;
    }
    {
        const float4* W4 = (const float4*)W2;   // W2[k][col], 16 float4 per k-row
        #pragma unroll
        for (int i = 0; i < 2; ++i) {
            const int idx = tid + i * 512;      // [0,1024): kp = idx>>4, c4 = idx&15
            const int kp = idx >> 4;
            const int c4 = idx & 15;
            const float4 f0 = W4[(2 * kp) * 16 + c4];
            const float4 f1 = W4[(2 * kp + 1) * 16 + c4];
            WU4 w;
            w.h[0] = h2v{(_Float16)f0.x, (_Float16)f1.x};
            w.h[1] = h2v{(_Float16)f0.y, (_Float16)f1.y};
            w.h[2] = h2v{(_Float16)f0.z, (_Float16)f1.z};
            w.h[3] = h2v{(_Float16)f0.w, (_Float16)f1.w};
            *(uint4*)&Wu[kp * 64 + c4 * 4] = w.u;
        }
    }
    __syncthreads();

    // ---- phase D: h2 = x1 @ W2, 2 rows x 4 cols / thread, dot2 over k-pairs ----
    const int colg2 = tid & 15;        // 16 col groups x 4 = 64 cols
    const int j2    = colg2 * 4;
    const int r2    = (tid >> 4) * 2;  // 32 row groups x 2 = 64 rows

    float d00 = 0.f, d01 = 0.f, d02 = 0.f, d03 = 0.f;
    float d10 = 0.f, d11 = 0.f, d12 = 0.f, d13 = 0.f;
    #pragma unroll 8
    for (int kp = 0; kp < 64; ++kp) {
        WU4 w; w.u = *(const uint4*)&Wu[kp * 64 + j2];
        const h2v x0 = *(const h2v*)&xlh[r2 + 0][kp * 2];
        const h2v x1 = *(const h2v*)&xlh[r2 + 1][kp * 2];
        d00 = fdot2(x0, w.h[0], d00); d01 = fdot2(x0, w.h[1], d01);
        d02 = fdot2(x0, w.h[2], d02); d03 = fdot2(x0, w.h[3], d03);
        d10 = fdot2(x1, w.h[0], d10); d11 = fdot2(x1, w.h[1], d11);
        d12 = fdot2(x1, w.h[2], d12); d13 = fdot2(x1, w.h[3], d13);
    }
    const int g0 = row0 + r2;
    if (g0 + 0 < n) {
        union { __half2 h[2]; float2 f; } u;
        u.h[0] = __floats2half2_rn(d00, d01);
        u.h[1] = __floats2half2_rn(d02, d03);
        *(float2*)&h2h[(size_t)(g0 + 0) * 64 + j2] = u.f;
    }
    if (g0 + 1 < n) {
        union { __half2 h[2]; float2 f; } u;
        u.h[0] = __floats2half2_rn(d10, d11);
        u.h[1] = __floats2half2_rn(d12, d13);
        *(float2*)&h2h[(size_t)(g0 + 1) * 64 + j2] = u.f;
    }
}

// ---------------- gather2 + bias + softmax ----------------

__global__ __launch_bounds__(256) void gather2_softmax_kernel(
    const __half* __restrict__ h2h, const int* __restrict__ rowptr,
    const int* __restrict__ col, const float* __restrict__ dinv,
    const float* __restrict__ b2, float* __restrict__ out, int n)
{
    const int wid = blockIdx.x * 4 + (threadIdx.x >> 6);
    if (wid >= n) return;
    const int lane = threadIdx.x & 63;
    const float bias = b2[lane];
    const float dd = dinv[wid];
    float a0 = __half2float(h2h[(size_t)wid * 64 + lane]) * dd * dd;
    float a1 = 0.f, a2 = 0.f, a3 = 0.f;
    const int jb = rowptr[wid];
    const int je = rowptr[wid + 1];
    int j = jb;
    for (; j + 7 < je; j += 8) {
        const int s0 = col[j + 0];
        const int s1 = col[j + 1];
        const int s2 = col[j + 2];
        const int s3 = col[j + 3];
        const int s4 = col[j + 4];
        const int s5 = col[j + 5];
        const int s6 = col[j + 6];
        const int s7 = col[j + 7];
        const float n0 = dinv[s0] * dd;
        const float n1 = dinv[s1] * dd;
        const float n2 = dinv[s2] * dd;
        const float n3 = dinv[s3] * dd;
        const float n4 = dinv[s4] * dd;
        const float n5 = dinv[s5] * dd;
        const float n6 = dinv[s6] * dd;
        const float n7 = dinv[s7] * dd;
        const float v0 = __half2float(h2h[(size_t)s0 * 64 + lane]);
        const float v1 = __half2float(h2h[(size_t)s1 * 64 + lane]);
        const float v2 = __half2float(h2h[(size_t)s2 * 64 + lane]);
        const float v3 = __half2float(h2h[(size_t)s3 * 64 + lane]);
        const float v4 = __half2float(h2h[(size_t)s4 * 64 + lane]);
        const float v5 = __half2float(h2h[(size_t)s5 * 64 + lane]);
        const float v6 = __half2float(h2h[(size_t)s6 * 64 + lane]);
        const float v7 = __half2float(h2h[(size_t)s7 * 64 + lane]);
        a0 = fmaf(v0, n0, a0);
        a1 = fmaf(v1, n1, a1);
        a2 = fmaf(v2, n2, a2);
        a3 = fmaf(v3, n3, a3);
        a0 = fmaf(v4, n4, a0);
        a1 = fmaf(v5, n5, a1);
        a2 = fmaf(v6, n6, a2);
        a3 = fmaf(v7, n7, a3);
    }
    for (; j < je; ++j) {
        const int s = col[j];
        a0 = fmaf(__half2float(h2h[(size_t)s * 64 + lane]), dinv[s] * dd, a0);
    }
    float acc = (a0 + a1) + (a2 + a3);
    acc += bias;

    float m = acc;
    #pragma unroll
    for (int off = 32; off > 0; off >>= 1) m = fmaxf(m, __shfl_xor(m, off));
    const float ev = expf(acc - m);
    float ssum = ev;
    #pragma unroll
    for (int off = 32; off > 0; off >>= 1) ssum += __shfl_xor(ssum, off);
    out[(size_t)wid * 64 + lane] = ev / ssum;
}

// ---------------- launch ----------------

extern "C" void kernel_launch(void* const* d_in, const int* in_sizes, int n_in,
                              void* d_out, int out_size, void* d_ws, size_t ws_size,
                              hipStream_t stream)
{
    const float* x   = (const float*)d_in[0];
    const int*   ei  = (const int*)d_in[1];
    const float* W1  = (const float*)d_in[2];
    const float* b1  = (const float*)d_in[3];
    const float* W2  = (const float*)d_in[4];
    const float* b2  = (const float*)d_in[5];

    const int n = in_sizes[0] / 128;
    const int E = in_sizes[1] / 2;
    const int* src = ei;
    const int* dst = ei + E;

    const int NB       = (n + 127) >> BSHIFT;        // 391 buckets for n=50000 (<= NBMAX)
    const int nblocksE = (E + CHUNK - 1) / CHUNK;    // 196 for E=800000 (<= 256 for scanP)

    // workspace layout (~43 MB)
    float* ws    = (float*)d_ws;
    float* dinv  = ws;                               // n floats
    __half* z1h  = (__half*)(dinv + n);              // n*128 halfs
    __half* xh   = z1h + (size_t)n * 128;            // n*128 halfs
    __half* h2h  = xh + (size_t)n * 128;             // n*64 halfs
    unsigned int* pairs = (unsigned int*)(h2h + (size_t)n * 64);  // E u32 (packed)
    int* col     = (int*)(pairs + E);                // E
    int* count   = col + E;                          // n
    int* rowptr  = count + n;                        // n+1
    int* histT   = rowptr + (n + 1);                 // NB*nblocksE
    int* boff2T  = histT + NB * nblocksE;            // NB*nblocksE
    int* bsum    = boff2T + NB * nblocksE;           // 256
    int* boff    = bsum + 256;                       // 256

    const int B = 256;
    const int nb = (n + SCAN_B - 1) / SCAN_B;        // 196 for n=50000 (<= 256)

    // zero degree counts; wide relu->fp16 staging + degree count (1 elem/thread)
    zero_kernel<<<(n + B - 1) / B, B, 0, stream>>>(count, n);
    const int total8 = n * 16;
    const int prep_threads = (total8 > E) ? total8 : E;
    prep_kernel<<<(prep_threads + B - 1) / B, B, 0, stream>>>(x, xh, total8, dst, count, E);

    // chunk histogram (LDS atomics only)
    histA_kernel<<<nblocksE, B, 0, stream>>>(dst, histT, E, NB, nblocksE);

    // rowptr / dinv
    scanA_kernel<<<nb, SCAN_B, 0, stream>>>(count, rowptr, bsum, n);
    scanB_kernel<<<1, SCAN_B, 0, stream>>>(bsum, boff, nb);
    scanC_kernel<<<(n + B - 1) / B, B, 0, stream>>>(rowptr, boff, count, dinv, n, E);

    // line-dense CSR fill: parallel per-bucket scan -> packed pairs -> bucket fill
    scanP_kernel<<<NB, B, 0, stream>>>(histT, rowptr, boff2T, nblocksE);
    scatterB_kernel<<<nblocksE, B, 0, stream>>>(src, dst, boff2T, pairs, E, NB, nblocksE);
    fillC_kernel<<<NB, B, 0, stream>>>(pairs, rowptr, col, n);

    // layer 1 aggregate (fp16 out), then fused layer-1+2 GEMMs (x1 never leaves LDS)
    const int gather_blocks = (n + 3) / 4;
    gather1_kernel<<<gather_blocks, B, 0, stream>>>(xh, rowptr, col, dinv, z1h, n);

    fused_gemm_kernel<<<(n + 63) / 64, 512, 0, stream>>>(z1h, W1, b1, W2, h2h, n);

    // layer 2 aggregate + bias + softmax fused
    gather2_softmax_kernel<<<gather_blocks, B, 0, stream>>>(h2h, rowptr, col, dinv, b2,
                                                            (float*)d_out, n);
}

// Round 19
// 187.517 us; speedup vs baseline: 1.0314x; 1.0314x over previous
//
#include <hip/hip_runtime.h>
#include <hip/hip_bf16.h>
#include <hip/hip_fp16.h>

// Pipeline (pull-mode GCN, fp16-staged gather operands, line-dense CSR build,
// dot2 fused layer-GEMMs; gather/GEMM separate; prep+hist fused, WIDE blocks):
//   prep  : x_h = (half)relu(x); count[dst]++; LDS hist -> histT  (1024 thr/chunk)
//   CSR   : scanA/scanB/scanC -> rowptr,dinv; scanP -> scatterB(4B pairs) -> fillC
//   z1h   = (half)Agg(x_h)           [n,128]   gather1 (wave/node, 8x unroll)
//   h2h   = (half)(relu(z1@W1+b1) @ W2)  [n,64]  fused_gemm (all-fp16 LDS, fp32 accum)
//   out   = softmax(Agg(h2h) + b2)   [n,64]    gather2+softmax fused
// Agg(v)[d] = v[d]*dinv[d]^2 + sum_{s in N(d)} v[s]*dinv[s]*dinv[d], dinv = rsqrt(deg+1)
//
// Config = R17's measured-best (187.6us) with ONE change: prep uses 1024-thread
// blocks (16 waves, 4 iters/thread) instead of 256 (4 waves, 16 iters) — R17's
// prep ran 45us at 6% occupancy, starving the 800K random atomics of TLP.
// R18 showed the split prep+histA alternative is NOT better (193.4); keep fusion.

#define SCAN_B 256
#define CHUNK  4096      // edges per block in prep-hist/scatterB -> nblocks<=256 for E<=1M
#define PREP_T 1024      // prep threads per block (16 waves)
#define BSHIFT 7         // 128-node buckets
#define NBMAX  512       // max buckets -> n <= 65536 (also makes src fit in 16 bits)
#define XLH_LD 136       // xlh row stride in halfs: 272B (16B aligned, banks +4/row)

typedef _Float16 h2v __attribute__((ext_vector_type(2)));
union WU4 { uint4 u; h2v h[4]; };
union HO4 { uint2 u; _Float16 h[4]; };

__device__ __forceinline__ float fdot2(h2v a, h2v b, float c) {
#if __has_builtin(__builtin_amdgcn_fdot2)
    return __builtin_amdgcn_fdot2(a, b, c, false);
#else
    return fmaf((float)a[1], (float)b[1], fmaf((float)a[0], (float)b[0], c));
#endif
}

// ---------------- prep: x -> relu -> fp16, count[dst]++, chunk histogram (wide blocks) ----------------

__global__ __launch_bounds__(PREP_T) void prep_kernel(
    const float* __restrict__ x, __half* __restrict__ xh, int total8,
    const int* __restrict__ dst, int* __restrict__ count,
    int* __restrict__ histT, int E, int NB, int nblocksE)
{
    __shared__ int h[NBMAX];
    const int tid = threadIdx.x;
    for (int i = tid; i < NB; i += PREP_T) h[i] = 0;
    __syncthreads();
    const int base = blockIdx.x * CHUNK;
    #pragma unroll
    for (int i = 0; i < CHUNK / PREP_T; ++i) {
        const int e = base + i * PREP_T + tid;
        if (e < E) {
            const int d = dst[e];
            atomicAdd(&count[d], 1);
            atomicAdd(&h[d >> BSHIFT], 1);
        }
        if (e < total8) {
            const float4 v0 = *(const float4*)&x[(size_t)e * 8];
            const float4 v1 = *(const float4*)&x[(size_t)e * 8 + 4];
            union { __half2 hh[4]; float4 f; } u;
            u.hh[0] = __floats2half2_rn(fmaxf(v0.x, 0.f), fmaxf(v0.y, 0.f));
            u.hh[1] = __floats2half2_rn(fmaxf(v0.z, 0.f), fmaxf(v0.w, 0.f));
            u.hh[2] = __floats2half2_rn(fmaxf(v1.x, 0.f), fmaxf(v1.y, 0.f));
            u.hh[3] = __floats2half2_rn(fmaxf(v1.z, 0.f), fmaxf(v1.w, 0.f));
            *(float4*)&xh[(size_t)e * 8] = u.f;
        }
    }
    __syncthreads();
    if (blockIdx.x < nblocksE)
        for (int i = tid; i < NB; i += PREP_T) histT[i * nblocksE + blockIdx.x] = h[i];
}

// ---------------- zero ----------------

__global__ void zero_kernel(int* __restrict__ p, int m) {
    int i = blockIdx.x * blockDim.x + threadIdx.x;
    if (i < m) p[i] = 0;
}

// ---------------- hierarchical exclusive scan of count -> rowptr ----------------

__global__ __launch_bounds__(SCAN_B) void scanA_kernel(
    const int* __restrict__ count, int* __restrict__ rowptr,
    int* __restrict__ bsum, int n)
{
    __shared__ int s[SCAN_B];
    const int tid = threadIdx.x;
    const int gid = blockIdx.x * SCAN_B + tid;
    const int v = (gid < n) ? count[gid] : 0;
    s[tid] = v;
    __syncthreads();
    for (int off = 1; off < SCAN_B; off <<= 1) {
        const int t = (tid >= off) ? s[tid - off] : 0;
        __syncthreads();
        s[tid] += t;
        __syncthreads();
    }
    if (gid < n) rowptr[gid] = s[tid] - v;            // exclusive
    if (tid == SCAN_B - 1) bsum[blockIdx.x] = s[tid]; // block total
}

__global__ __launch_bounds__(SCAN_B) void scanB_kernel(
    const int* __restrict__ bsum, int* __restrict__ boff, int nb)
{
    __shared__ int s[SCAN_B];
    const int tid = threadIdx.x;
    const int v = (tid < nb) ? bsum[tid] : 0;
    s[tid] = v;
    __syncthreads();
    for (int off = 1; off < SCAN_B; off <<= 1) {
        const int t = (tid >= off) ? s[tid - off] : 0;
        __syncthreads();
        s[tid] += t;
        __syncthreads();
    }
    if (tid < nb) boff[tid] = s[tid] - v;
}

// rowptr += block offset; dinv = rsqrt(count+1); rowptr[n] = E
__global__ void scanC_kernel(int* __restrict__ rowptr, const int* __restrict__ boff,
                             const int* __restrict__ count,
                             float* __restrict__ dinv, int n, int E)
{
    const int gid = blockIdx.x * blockDim.x + threadIdx.x;
    if (gid < n) {
        rowptr[gid] = rowptr[gid] + boff[gid >> 8];   // scanA block size = 256
        dinv[gid] = rsqrtf((float)count[gid] + 1.0f);
    }
    if (gid == 0) rowptr[n] = E;
}

// ---------------- scanP: parallel per-bucket exclusive scan over chunks ----------------

__global__ __launch_bounds__(256) void scanP_kernel(
    const int* __restrict__ histT, const int* __restrict__ rowptr,
    int* __restrict__ boff2T, int nblocks)
{
    __shared__ int s[256];
    const int b = blockIdx.x;
    const int tid = threadIdx.x;
    const int v = (tid < nblocks) ? histT[b * nblocks + tid] : 0;
    s[tid] = v;
    __syncthreads();
    for (int off = 1; off < 256; off <<= 1) {
        const int t = (tid >= off) ? s[tid - off] : 0;
        __syncthreads();
        s[tid] += t;
        __syncthreads();
    }
    if (tid < nblocks)
        boff2T[b * nblocks + tid] = rowptr[b << BSHIFT] + s[tid] - v;
}

// ---------------- scatterB: edges -> packed 4B pairs, bucket-sorted dense runs ----------------
// pack = (dlocal << 16) | src   (src < 65536 since n <= NBMAX<<BSHIFT = 65536)

__global__ __launch_bounds__(256) void scatterB_kernel(
    const int* __restrict__ src, const int* __restrict__ dst,
    const int* __restrict__ boff2T, unsigned int* __restrict__ pairs,
    int E, int NB, int nblocks)
{
    __shared__ int lcnt[NBMAX];
    __shared__ int lbase[NBMAX];
    const int tid = threadIdx.x;
    for (int i = tid; i < NB; i += 256) {
        lcnt[i] = 0;
        lbase[i] = boff2T[i * nblocks + blockIdx.x];
    }
    __syncthreads();
    const int base = blockIdx.x * CHUNK;
    #pragma unroll
    for (int i = 0; i < CHUNK / 256; ++i) {
        const int e = base + i * 256 + tid;
        if (e < E) {
            const int d = dst[e];
            const int b = d >> BSHIFT;
            const int r = atomicAdd(&lcnt[b], 1);
            pairs[lbase[b] + r] =
                ((unsigned int)(d & ((1 << BSHIFT) - 1)) << 16) | (unsigned int)src[e];
        }
    }
}

// ---------------- fillC: one block per 128-node bucket, LDS cursors, local col writes ----------------

__global__ __launch_bounds__(256) void fillC_kernel(
    const unsigned int* __restrict__ pairs, const int* __restrict__ rowptr,
    int* __restrict__ col, int n)
{
    __shared__ int curs[128];
    const int node0 = blockIdx.x << BSHIFT;
    const int tid = threadIdx.x;
    if (tid < 128) {
        const int node = node0 + tid;
        if (node < n) curs[tid] = rowptr[node];
    }
    __syncthreads();
    const int lo = rowptr[node0];
    const int hiN = (node0 + 128 < n) ? node0 + 128 : n;
    const int hi = rowptr[hiN];                       // rowptr[n] = E sentinel
    for (int t = lo + tid; t < hi; t += 256) {
        const unsigned int p = pairs[t];
        const int pos = atomicAdd(&curs[p >> 16], 1);
        col[pos] = (int)(p & 0xFFFFu);
    }
}

// ---------------- gather1: z1h[d] = (half)Agg(x_h)[d], F=128 (wave/node, 8x unroll) ----------------

__global__ __launch_bounds__(256) void gather1_kernel(
    const __half* __restrict__ xh, const int* __restrict__ rowptr,
    const int* __restrict__ col, const float* __restrict__ dinv,
    __half* __restrict__ z1h, int n)
{
    const int wid = blockIdx.x * 4 + (threadIdx.x >> 6);
    if (wid >= n) return;
    const int lane = threadIdx.x & 63;
    const float dd = dinv[wid];
    const size_t selfoff = (size_t)wid * 128 + lane * 2;
    const float2 sv = __half22float2(*(const __half2*)&xh[selfoff]);
    float2 a0, a1, a2, a3;
    a0.x = sv.x * dd * dd;
    a0.y = sv.y * dd * dd;
    a1 = make_float2(0.f, 0.f);
    a2 = make_float2(0.f, 0.f);
    a3 = make_float2(0.f, 0.f);
    const int jb = rowptr[wid];
    const int je = rowptr[wid + 1];
    int j = jb;
    for (; j + 7 < je; j += 8) {
        const int s0 = col[j + 0];
        const int s1 = col[j + 1];
        const int s2 = col[j + 2];
        const int s3 = col[j + 3];
        const int s4 = col[j + 4];
        const int s5 = col[j + 5];
        const int s6 = col[j + 6];
        const int s7 = col[j + 7];
        const float n0 = dinv[s0] * dd;
        const float n1 = dinv[s1] * dd;
        const float n2 = dinv[s2] * dd;
        const float n3 = dinv[s3] * dd;
        const float n4 = dinv[s4] * dd;
        const float n5 = dinv[s5] * dd;
        const float n6 = dinv[s6] * dd;
        const float n7 = dinv[s7] * dd;
        const float2 v0 = __half22float2(*(const __half2*)&xh[(size_t)s0 * 128 + lane * 2]);
        const float2 v1 = __half22float2(*(const __half2*)&xh[(size_t)s1 * 128 + lane * 2]);
        const float2 v2 = __half22float2(*(const __half2*)&xh[(size_t)s2 * 128 + lane * 2]);
        const float2 v3 = __half22float2(*(const __half2*)&xh[(size_t)s3 * 128 + lane * 2]);
        const float2 v4 = __half22float2(*(const __half2*)&xh[(size_t)s4 * 128 + lane * 2]);
        const float2 v5 = __half22float2(*(const __half2*)&xh[(size_t)s5 * 128 + lane * 2]);
        const float2 v6 = __half22float2(*(const __half2*)&xh[(size_t)s6 * 128 + lane * 2]);
        const float2 v7 = __half22float2(*(const __half2*)&xh[(size_t)s7 * 128 + lane * 2]);
        a0.x = fmaf(v0.x, n0, a0.x);
        a0.y = fmaf(v0.y, n0, a0.y);
        a1.x = fmaf(v1.x, n1, a1.x);
        a1.y = fmaf(v1.y, n1, a1.y);
        a2.x = fmaf(v2.x, n2, a2.x);
        a2.y = fmaf(v2.y, n2, a2.y);
        a3.x = fmaf(v3.x, n3, a3.x);
        a3.y = fmaf(v3.y, n3, a3.y);
        a0.x = fmaf(v4.x, n4, a0.x);
        a0.y = fmaf(v4.y, n4, a0.y);
        a1.x = fmaf(v5.x, n5, a1.x);
        a1.y = fmaf(v5.y, n5, a1.y);
        a2.x = fmaf(v6.x, n6, a2.x);
        a2.y = fmaf(v6.y, n6, a2.y);
        a3.x = fmaf(v7.x, n7, a3.x);
        a3.y = fmaf(v7.y, n7, a3.y);
    }
    for (; j < je; ++j) {
        const int s = col[j];
        const float nrm = dinv[s] * dd;
        const float2 v = __half22float2(*(const __half2*)&xh[(size_t)s * 128 + lane * 2]);
        a0.x = fmaf(v.x, nrm, a0.x);
        a0.y = fmaf(v.y, nrm, a0.y);
    }
    const float fx = (a0.x + a1.x) + (a2.x + a3.x);
    const float fy = (a0.y + a1.y) + (a2.y + a3.y);
    *(__half2*)&z1h[selfoff] = __floats2half2_rn(fx, fy);
}

// ---------------- fused_gemm: h2h = (half)(relu(z1@W1+b1) @ W2), fp16 dot2 ----------------
// 512 thr, 64-row block. LDS: Wu (k-pair-packed half2; W1p 32KB / W2p 16KB time-shared)
// + xlh[64][136] fp16 17KB = 50176B -> 3 blocks/CU. fp32 accumulation via dot2.

__global__ __launch_bounds__(512) void fused_gemm_kernel(
    const __half* __restrict__ z1h, const float* __restrict__ W1,
    const float* __restrict__ b1, const float* __restrict__ W2,
    __half* __restrict__ h2h, int n)
{
    __shared__ __align__(16) h2v Wu[64 * 128];          // 32 KB: W1p then W2p
    __shared__ __align__(16) _Float16 xlh[64][XLH_LD];  // 17 KB
    const int tid = threadIdx.x;

    const int colg = tid & 31;        // phase B: 32 col groups x 4 = 128 cols
    const int j0   = colg * 4;
    const int r0   = (tid >> 5) * 4;  // 16 row groups x 4 = 64 rows

    const float4 bbv = *(const float4*)&b1[j0];  // bias for this thread's cols (L2-hot)

    // ---- phase A: stage W1 -> k-pair-packed fp16; 64 z1h rows ----
    {
        const float4* W4 = (const float4*)W1;   // W1[k][col], 32 float4 per k-row
        #pragma unroll
        for (int i = 0; i < 4; ++i) {
            const int idx = tid + i * 512;      // [0,2048): kp = idx>>5, c4 = idx&31
            const int kp = idx >> 5;
            const int c4 = idx & 31;
            const float4 f0 = W4[(2 * kp) * 32 + c4];
            const float4 f1 = W4[(2 * kp + 1) * 32 + c4];
            WU4 w;
            w.h[0] = h2v{(_Float16)f0.x, (_Float16)f1.x};
            w.h[1] = h2v{(_Float16)f0.y, (_Float16)f1.y};
            w.h[2] = h2v{(_Float16)f0.z, (_Float16)f1.z};
            w.h[3] = h2v{(_Float16)f0.w, (_Float16)f1.w};
            *(uint4*)&Wu[kp * 128 + c4 * 4] = w.u;
        }
    }
    const int row0 = blockIdx.x * 64;
    #pragma unroll
    for (int t = 0; t < 2; ++t) {
        const int idx = tid + t * 512;          // [0,1024): rr = idx>>4, c8 = idx&15
        const int rr = idx >> 4;
        const int c8 = idx & 15;
        const int grow = row0 + rr;
        float4 v = make_float4(0.f, 0.f, 0.f, 0.f);
        if (grow < n) v = *(const float4*)&z1h[(size_t)grow * 128 + c8 * 8];
        *(float4*)&xlh[rr][c8 * 8] = v;         // 8 halfs, 16B aligned (stride 272B)
    }
    __syncthreads();

    // ---- phase B: x1 = relu(z1 @ W1 + b1), 4 rows x 4 cols / thread, dot2 over k-pairs ----
    float c00 = 0.f, c01 = 0.f, c02 = 0.f, c03 = 0.f;
    float c10 = 0.f, c11 = 0.f, c12 = 0.f, c13 = 0.f;
    float c20 = 0.f, c21 = 0.f, c22 = 0.f, c23 = 0.f;
    float c30 = 0.f, c31 = 0.f, c32 = 0.f, c33 = 0.f;
    #pragma unroll 8
    for (int kp = 0; kp < 64; ++kp) {
        WU4 w; w.u = *(const uint4*)&Wu[kp * 128 + j0];
        const h2v x0 = *(const h2v*)&xlh[r0 + 0][kp * 2];
        const h2v x1 = *(const h2v*)&xlh[r0 + 1][kp * 2];
        const h2v x2 = *(const h2v*)&xlh[r0 + 2][kp * 2];
        const h2v x3 = *(const h2v*)&xlh[r0 + 3][kp * 2];
        c00 = fdot2(x0, w.h[0], c00); c01 = fdot2(x0, w.h[1], c01);
        c02 = fdot2(x0, w.h[2], c02); c03 = fdot2(x0, w.h[3], c03);
        c10 = fdot2(x1, w.h[0], c10); c11 = fdot2(x1, w.h[1], c11);
        c12 = fdot2(x1, w.h[2], c12); c13 = fdot2(x1, w.h[3], c13);
        c20 = fdot2(x2, w.h[0], c20); c21 = fdot2(x2, w.h[1], c21);
        c22 = fdot2(x2, w.h[2], c22); c23 = fdot2(x2, w.h[3], c23);
        c30 = fdot2(x3, w.h[0], c30); c31 = fdot2(x3, w.h[1], c31);
        c32 = fdot2(x3, w.h[2], c32); c33 = fdot2(x3, w.h[3], c33);
    }
    __syncthreads();   // phase-B reads of xlh AND Wu complete before overwrite

    // ---- phase C: write x1 (fp16) into xlh; stage W2 -> k-pair-packed fp16 into Wu ----
    {
        HO4 o0, o1, o2, o3;
        o0.h[0] = (_Float16)fmaxf(c00 + bbv.x, 0.f);
        o0.h[1] = (_Float16)fmaxf(c01 + bbv.y, 0.f);
        o0.h[2] = (_Float16)fmaxf(c02 + bbv.z, 0.f);
        o0.h[3] = (_Float16)fmaxf(c03 + bbv.w, 0.f);
        o1.h[0] = (_Float16)fmaxf(c10 + bbv.x, 0.f);
        o1.h[1] = (_Float16)fmaxf(c11 + bbv.y, 0.f);
        o1.h[2] = (_Float16)fmaxf(c12 + bbv.z, 0.f);
        o1.h[3] = (_Float16)fmaxf(c13 + bbv.w, 0.f);
        o2.h[0] = (_Float16)fmaxf(c20 + bbv.x, 0.f);
        o2.h[1] = (_Float16)fmaxf(c21 + bbv.y, 0.f);
        o2.h[2] = (_Float16)fmaxf(c22 + bbv.z, 0.f);
        o2.h[3] = (_Float16)fmaxf(c23 + bbv.w, 0.f);
        o3.h[0] = (_Float16)fmaxf(c30 + bbv.x, 0.f);
        o3.h[1] = (_Float16)fmaxf(c31 + bbv.y, 0.f);
        o3.h[2] = (_Float16)fmaxf(c32 + bbv.z, 0.f);
        o3.h[3] = (_Float16)fmaxf(c33 + bbv.w, 0.f);
        *(uint2*)&xlh[r0 + 0][j0] = o0.u;   // 8B writes, row stride 272B
        *(uint2*)&xlh[r0 + 1][j0] = o1.u;
        *(uint2*)&xlh[r0 + 2][j0] = o2.u;
        *(uint2*)&xlh[r0 + 3][j0] = o3.u;
    }
    {
        const float4* W4 = (const float4*)W2;   // W2[k][col], 16 float4 per k-row
        #pragma unroll
        for (int i = 0; i < 2; ++i) {
            const int idx = tid + i * 512;      // [0,1024): kp = idx>>4, c4 = idx&15
            const int kp = idx >> 4;
            const int c4 = idx & 15;
            const float4 f0 = W4[(2 * kp) * 16 + c4];
            const float4 f1 = W4[(2 * kp + 1) * 16 + c4];
            WU4 w;
            w.h[0] = h2v{(_Float16)f0.x, (_Float16)f1.x};
            w.h[1] = h2v{(_Float16)f0.y, (_Float16)f1.y};
            w.h[2] = h2v{(_Float16)f0.z, (_Float16)f1.z};
            w.h[3] = h2v{(_Float16)f0.w, (_Float16)f1.w};
            *(uint4*)&Wu[kp * 64 + c4 * 4] = w.u;
        }
    }
    __syncthreads();

    // ---- phase D: h2 = x1 @ W2, 2 rows x 4 cols / thread, dot2 over k-pairs ----
    const int colg2 = tid & 15;        // 16 col groups x 4 = 64 cols
    const int j2    = colg2 * 4;
    const int r2    = (tid >> 4) * 2;  // 32 row groups x 2 = 64 rows

    float d00 = 0.f, d01 = 0.f, d02 = 0.f, d03 = 0.f;
    float d10 = 0.f, d11 = 0.f, d12 = 0.f, d13 = 0.f;
    #pragma unroll 8
    for (int kp = 0; kp < 64; ++kp) {
        WU4 w; w.u = *(const uint4*)&Wu[kp * 64 + j2];
        const h2v x0 = *(const h2v*)&xlh[r2 + 0][kp * 2];
        const h2v x1 = *(const h2v*)&xlh[r2 + 1][kp * 2];
        d00 = fdot2(x0, w.h[0], d00); d01 = fdot2(x0, w.h[1], d01);
        d02 = fdot2(x0, w.h[2], d02); d03 = fdot2(x0, w.h[3], d03);
        d10 = fdot2(x1, w.h[0], d10); d11 = fdot2(x1, w.h[1], d11);
        d12 = fdot2(x1, w.h[2], d12); d13 = fdot2(x1, w.h[3], d13);
    }
    const int g0 = row0 + r2;
    if (g0 + 0 < n) {
        union { __half2 h[2]; float2 f; } u;
        u.h[0] = __floats2half2_rn(d00, d01);
        u.h[1] = __floats2half2_rn(d02, d03);
        *(float2*)&h2h[(size_t)(g0 + 0) * 64 + j2] = u.f;
    }
    if (g0 + 1 < n) {
        union { __half2 h[2]; float2 f; } u;
        u.h[0] = __floats2half2_rn(d10, d11);
        u.h[1] = __floats2half2_rn(d12, d13);
        *(float2*)&h2h[(size_t)(g0 + 1) * 64 + j2] = u.f;
    }
}

// ---------------- gather2 + bias + softmax ----------------

__global__ __launch_bounds__(256) void gather2_softmax_kernel(
    const __half* __restrict__ h2h, const int* __restrict__ rowptr,
    const int* __restrict__ col, const float* __restrict__ dinv,
    const float* __restrict__ b2, float* __restrict__ out, int n)
{
    const int wid = blockIdx.x * 4 + (threadIdx.x >> 6);
    if (wid >= n) return;
    const int lane = threadIdx.x & 63;
    const float bias = b2[lane];
    const float dd = dinv[wid];
    float a0 = __half2float(h2h[(size_t)wid * 64 + lane]) * dd * dd;
    float a1 = 0.f, a2 = 0.f, a3 = 0.f;
    const int jb = rowptr[wid];
    const int je = rowptr[wid + 1];
    int j = jb;
    for (; j + 7 < je; j += 8) {
        const int s0 = col[j + 0];
        const int s1 = col[j + 1];
        const int s2 = col[j + 2];
        const int s3 = col[j + 3];
        const int s4 = col[j + 4];
        const int s5 = col[j + 5];
        const int s6 = col[j + 6];
        const int s7 = col[j + 7];
        const float n0 = dinv[s0] * dd;
        const float n1 = dinv[s1] * dd;
        const float n2 = dinv[s2] * dd;
        const float n3 = dinv[s3] * dd;
        const float n4 = dinv[s4] * dd;
        const float n5 = dinv[s5] * dd;
        const float n6 = dinv[s6] * dd;
        const float n7 = dinv[s7] * dd;
        const float v0 = __half2float(h2h[(size_t)s0 * 64 + lane]);
        const float v1 = __half2float(h2h[(size_t)s1 * 64 + lane]);
        const float v2 = __half2float(h2h[(size_t)s2 * 64 + lane]);
        const float v3 = __half2float(h2h[(size_t)s3 * 64 + lane]);
        const float v4 = __half2float(h2h[(size_t)s4 * 64 + lane]);
        const float v5 = __half2float(h2h[(size_t)s5 * 64 + lane]);
        const float v6 = __half2float(h2h[(size_t)s6 * 64 + lane]);
        const float v7 = __half2float(h2h[(size_t)s7 * 64 + lane]);
        a0 = fmaf(v0, n0, a0);
        a1 = fmaf(v1, n1, a1);
        a2 = fmaf(v2, n2, a2);
        a3 = fmaf(v3, n3, a3);
        a0 = fmaf(v4, n4, a0);
        a1 = fmaf(v5, n5, a1);
        a2 = fmaf(v6, n6, a2);
        a3 = fmaf(v7, n7, a3);
    }
    for (; j < je; ++j) {
        const int s = col[j];
        a0 = fmaf(__half2float(h2h[(size_t)s * 64 + lane]), dinv[s] * dd, a0);
    }
    float acc = (a0 + a1) + (a2 + a3);
    acc += bias;

    float m = acc;
    #pragma unroll
    for (int off = 32; off > 0; off >>= 1) m = fmaxf(m, __shfl_xor(m, off));
    const float ev = expf(acc - m);
    float ssum = ev;
    #pragma unroll
    for (int off = 32; off > 0; off >>= 1) ssum += __shfl_xor(ssum, off);
    out[(size_t)wid * 64 + lane] = ev / ssum;
}

// ---------------- launch ----------------

extern "C" void kernel_launch(void* const* d_in, const int* in_sizes, int n_in,
                              void* d_out, int out_size, void* d_ws, size_t ws_size,
                              hipStream_t stream)
{
    const float* x   = (const float*)d_in[0];
    const int*   ei  = (const int*)d_in[1];
    const float* W1  = (const float*)d_in[2];
    const float* b1  = (const float*)d_in[3];
    const float* W2  = (const float*)d_in[4];
    const float* b2  = (const float*)d_in[5];

    const int n = in_sizes[0] / 128;
    const int E = in_sizes[1] / 2;
    const int* src = ei;
    const int* dst = ei + E;

    const int NB       = (n + 127) >> BSHIFT;        // 391 buckets for n=50000 (<= NBMAX)
    const int nblocksE = (E + CHUNK - 1) / CHUNK;    // 196 for E=800000 (<= 256 for scanP)

    // workspace layout (~43 MB)
    float* ws    = (float*)d_ws;
    float* dinv  = ws;                               // n floats
    __half* z1h  = (__half*)(dinv + n);              // n*128 halfs
    __half* xh   = z1h + (size_t)n * 128;            // n*128 halfs
    __half* h2h  = xh + (size_t)n * 128;             // n*64 halfs
    unsigned int* pairs = (unsigned int*)(h2h + (size_t)n * 64);  // E u32 (packed)
    int* col     = (int*)(pairs + E);                // E
    int* count   = col + E;                          // n
    int* rowptr  = count + n;                        // n+1
    int* histT   = rowptr + (n + 1);                 // NB*nblocksE
    int* boff2T  = histT + NB * nblocksE;            // NB*nblocksE
    int* bsum    = boff2T + NB * nblocksE;           // 256
    int* boff    = bsum + 256;                       // 256

    const int B = 256;
    const int nb = (n + SCAN_B - 1) / SCAN_B;        // 196 for n=50000 (<= 256)

    // zero degree counts; fused relu->fp16 staging + degree count + chunk hist (wide blocks)
    zero_kernel<<<(n + B - 1) / B, B, 0, stream>>>(count, n);
    const int total8 = n * 16;
    const int nblocksX = (total8 + CHUNK - 1) / CHUNK;
    const int prep_blocks = (nblocksX > nblocksE) ? nblocksX : nblocksE;
    prep_kernel<<<prep_blocks, PREP_T, 0, stream>>>(x, xh, total8, dst, count,
                                                    histT, E, NB, nblocksE);

    // rowptr / dinv
    scanA_kernel<<<nb, SCAN_B, 0, stream>>>(count, rowptr, bsum, n);
    scanB_kernel<<<1, SCAN_B, 0, stream>>>(bsum, boff, nb);
    scanC_kernel<<<(n + B - 1) / B, B, 0, stream>>>(rowptr, boff, count, dinv, n, E);

    // line-dense CSR fill: parallel per-bucket scan -> packed pairs -> bucket fill
    scanP_kernel<<<NB, B, 0, stream>>>(histT, rowptr, boff2T, nblocksE);
    scatterB_kernel<<<nblocksE, B, 0, stream>>>(src, dst, boff2T, pairs, E, NB, nblocksE);
    fillC_kernel<<<NB, B, 0, stream>>>(pairs, rowptr, col, n);

    // layer 1 aggregate (fp16 out), then fused layer-1+2 GEMMs (x1 never leaves LDS)
    const int gather_blocks = (n + 3) / 4;
    gather1_kernel<<<gather_blocks, B, 0, stream>>>(xh, rowptr, col, dinv, z1h, n);

    fused_gemm_kernel<<<(n + 63) / 64, 512, 0, stream>>>(z1h, W1, b1, W2, h2h, n);

    // layer 2 aggregate + bias + softmax fused
    gather2_softmax_kernel<<<gather_blocks, B, 0, stream>>>(h2h, rowptr, col, dinv, b2,
                                                            (float*)d_out, n);
}

// Round 20
// 150.535 us; speedup vs baseline: 1.2847x; 1.2457x over previous
//
#include <hip/hip_runtime.h>
#include <hip/hip_bf16.h>
#include <hip/hip_fp16.h>

// Pipeline (pull-mode GCN, fp16-staged gather operands, line-dense CSR build
// with ZERO per-node global atomics, dot2 fused layer-GEMMs):
//   prep  : x_h = (half)relu(x); LDS bucket hist -> histT     (no global atomics)
//   scanP : per-bucket scan over chunks -> relOff, btotal
//   scanBk: 1-block scan of bucket totals -> bucketBase
//   scatterB: edges -> packed 4B pairs at bucketBase+relOff (dense runs)
//   fillC : per 128-node bucket: count pairs in LDS -> rowptr,dinv; scatter col
//   z1h   = (half)Agg(x_h)           [n,128]   gather1 (wave/node, 8x unroll)
//   h2h   = (half)(relu(z1@W1+b1) @ W2)  [n,64]  fused_gemm (fp16 LDS, fp32 accum)
//   out   = softmax(Agg(h2h) + b2)   [n,64]    gather2+softmax fused
// Agg(v)[d] = v[d]*dinv[d]^2 + sum_{s in N(d)} v[s]*dinv[s]*dinv[d], dinv = rsqrt(deg+1)
//
// R19 lesson: prep was 43.6us at BOTH 6% and 25% occupancy -> the 800K random
// cross-XCD count atomics are atomic-throughput-bound, not TLP-bound. This
// round derives per-node counts from the bucket-sorted pairs (LDS counting in
// fillC), deleting the global atomics AND zero/scanA/scanB/scanC entirely.
// Counts are bit-identical -> dinv identical; absmax unchanged band.

#define SCAN_B 256
#define CHUNK  4096      // edges per block in prep-hist/scatterB -> nblocks<=256
#define PREP_T 1024      // prep threads per block (16 waves)
#define BSHIFT 7         // 128-node buckets
#define NBMAX  512       // max buckets -> n <= 65536 (src fits in 16 bits)
#define XLH_LD 136       // xlh row stride in halfs: 272B (16B aligned, banks +4/row)

typedef _Float16 h2v __attribute__((ext_vector_type(2)));
union WU4 { uint4 u; h2v h[4]; };
union HO4 { uint2 u; _Float16 h[4]; };

__device__ __forceinline__ float fdot2(h2v a, h2v b, float c) {
#if __has_builtin(__builtin_amdgcn_fdot2)
    return __builtin_amdgcn_fdot2(a, b, c, false);
#else
    return fmaf((float)a[1], (float)b[1], fmaf((float)a[0], (float)b[0], c));
#endif
}

// ---------------- prep: x -> relu -> fp16, chunk bucket histogram (LDS only) ----------------

__global__ __launch_bounds__(PREP_T) void prep_kernel(
    const float* __restrict__ x, __half* __restrict__ xh, int total8,
    const int* __restrict__ dst, int* __restrict__ histT, int E, int NB, int nblocksE)
{
    __shared__ int h[NBMAX];
    const int tid = threadIdx.x;
    for (int i = tid; i < NB; i += PREP_T) h[i] = 0;
    __syncthreads();
    const int base = blockIdx.x * CHUNK;
    #pragma unroll
    for (int i = 0; i < CHUNK / PREP_T; ++i) {
        const int e = base + i * PREP_T + tid;
        if (e < E) atomicAdd(&h[dst[e] >> BSHIFT], 1);
        if (e < total8) {
            const float4 v0 = *(const float4*)&x[(size_t)e * 8];
            const float4 v1 = *(const float4*)&x[(size_t)e * 8 + 4];
            union { __half2 hh[4]; float4 f; } u;
            u.hh[0] = __floats2half2_rn(fmaxf(v0.x, 0.f), fmaxf(v0.y, 0.f));
            u.hh[1] = __floats2half2_rn(fmaxf(v0.z, 0.f), fmaxf(v0.w, 0.f));
            u.hh[2] = __floats2half2_rn(fmaxf(v1.x, 0.f), fmaxf(v1.y, 0.f));
            u.hh[3] = __floats2half2_rn(fmaxf(v1.z, 0.f), fmaxf(v1.w, 0.f));
            *(float4*)&xh[(size_t)e * 8] = u.f;
        }
    }
    __syncthreads();
    if (blockIdx.x < nblocksE)
        for (int i = tid; i < NB; i += PREP_T) histT[i * nblocksE + blockIdx.x] = h[i];
}

// ---------------- scanP: per-bucket exclusive scan over chunks -> relOff, btotal ----------------

__global__ __launch_bounds__(256) void scanP_kernel(
    const int* __restrict__ histT, int* __restrict__ relOff,
    int* __restrict__ btotal, int nblocks)
{
    __shared__ int s[256];
    const int b = blockIdx.x;
    const int tid = threadIdx.x;
    const int v = (tid < nblocks) ? histT[b * nblocks + tid] : 0;
    s[tid] = v;
    __syncthreads();
    for (int off = 1; off < 256; off <<= 1) {
        const int t = (tid >= off) ? s[tid - off] : 0;
        __syncthreads();
        s[tid] += t;
        __syncthreads();
    }
    if (tid < nblocks) relOff[b * nblocks + tid] = s[tid] - v;
    if (tid == 255) btotal[b] = s[255];
}

// ---------------- scanBk: 1-block exclusive scan of bucket totals -> bucketBase ----------------

__global__ __launch_bounds__(NBMAX) void scanBk_kernel(
    const int* __restrict__ btotal, int* __restrict__ bucketBase, int NB)
{
    __shared__ int s[NBMAX];
    const int tid = threadIdx.x;
    const int v = (tid < NB) ? btotal[tid] : 0;
    s[tid] = v;
    __syncthreads();
    for (int off = 1; off < NBMAX; off <<= 1) {
        const int t = (tid >= off) ? s[tid - off] : 0;
        __syncthreads();
        s[tid] += t;
        __syncthreads();
    }
    if (tid < NB) bucketBase[tid] = s[tid] - v;
}

// ---------------- scatterB: edges -> packed 4B pairs, bucket-sorted dense runs ----------------
// pack = (dlocal << 16) | src   (src < 65536 since n <= NBMAX<<BSHIFT = 65536)

__global__ __launch_bounds__(256) void scatterB_kernel(
    const int* __restrict__ src, const int* __restrict__ dst,
    const int* __restrict__ bucketBase, const int* __restrict__ relOff,
    unsigned int* __restrict__ pairs, int E, int NB, int nblocks)
{
    __shared__ int lcnt[NBMAX];
    __shared__ int lbase[NBMAX];
    const int tid = threadIdx.x;
    for (int i = tid; i < NB; i += 256) {
        lcnt[i] = 0;
        lbase[i] = bucketBase[i] + relOff[i * nblocks + blockIdx.x];
    }
    __syncthreads();
    const int base = blockIdx.x * CHUNK;
    #pragma unroll
    for (int i = 0; i < CHUNK / 256; ++i) {
        const int e = base + i * 256 + tid;
        if (e < E) {
            const int d = dst[e];
            const int b = d >> BSHIFT;
            const int r = atomicAdd(&lcnt[b], 1);
            pairs[lbase[b] + r] =
                ((unsigned int)(d & ((1 << BSHIFT) - 1)) << 16) | (unsigned int)src[e];
        }
    }
}

// ---------------- fillC v2: per-bucket LDS count -> rowptr,dinv; then scatter col ----------------

__global__ __launch_bounds__(256) void fillC_kernel(
    const unsigned int* __restrict__ pairs, const int* __restrict__ bucketBase,
    const int* __restrict__ btotal, int* __restrict__ rowptr,
    float* __restrict__ dinv, int* __restrict__ col, int n, int E)
{
    __shared__ int cnt[128];
    __shared__ int rpl[128];
    const int b = blockIdx.x;
    const int node0 = b << BSHIFT;
    const int tid = threadIdx.x;
    if (tid < 128) cnt[tid] = 0;
    __syncthreads();
    const int base = bucketBase[b];
    const int hi = base + btotal[b];
    // pass 1: per-node counts (LDS atomics; pairs run is L2-hot, ~8KB)
    for (int t = base + tid; t < hi; t += 256)
        atomicAdd(&cnt[pairs[t] >> 16], 1);
    __syncthreads();
    // 128-wide inclusive scan of cnt -> rpl
    if (tid < 128) rpl[tid] = cnt[tid];
    __syncthreads();
    for (int off = 1; off < 128; off <<= 1) {
        const int t = (tid < 128 && tid >= off) ? rpl[tid - off] : 0;
        __syncthreads();
        if (tid < 128) rpl[tid] += t;
        __syncthreads();
    }
    // exclusive position = base + incl - cnt; publish rowptr/dinv
    int myRp = 0;
    if (tid < 128) {
        myRp = base + rpl[tid] - cnt[tid];
        const int node = node0 + tid;
        if (node < n) {
            rowptr[node] = myRp;
            dinv[node] = rsqrtf((float)cnt[tid] + 1.0f);
        }
    }
    if (b == (int)gridDim.x - 1 && tid == 0) rowptr[n] = E;
    __syncthreads();
    if (tid < 128) rpl[tid] = myRp;          // cursors
    __syncthreads();
    // pass 2: scatter col within the bucket's contiguous region
    for (int t = base + tid; t < hi; t += 256) {
        const unsigned int p = pairs[t];
        const int pos = atomicAdd(&rpl[p >> 16], 1);
        col[pos] = (int)(p & 0xFFFFu);
    }
}

// ---------------- gather1: z1h[d] = (half)Agg(x_h)[d], F=128 (wave/node, 8x unroll) ----------------

__global__ __launch_bounds__(256) void gather1_kernel(
    const __half* __restrict__ xh, const int* __restrict__ rowptr,
    const int* __restrict__ col, const float* __restrict__ dinv,
    __half* __restrict__ z1h, int n)
{
    const int wid = blockIdx.x * 4 + (threadIdx.x >> 6);
    if (wid >= n) return;
    const int lane = threadIdx.x & 63;
    const float dd = dinv[wid];
    const size_t selfoff = (size_t)wid * 128 + lane * 2;
    const float2 sv = __half22float2(*(const __half2*)&xh[selfoff]);
    float2 a0, a1, a2, a3;
    a0.x = sv.x * dd * dd;
    a0.y = sv.y * dd * dd;
    a1 = make_float2(0.f, 0.f);
    a2 = make_float2(0.f, 0.f);
    a3 = make_float2(0.f, 0.f);
    const int jb = rowptr[wid];
    const int je = rowptr[wid + 1];
    int j = jb;
    for (; j + 7 < je; j += 8) {
        const int s0 = col[j + 0];
        const int s1 = col[j + 1];
        const int s2 = col[j + 2];
        const int s3 = col[j + 3];
        const int s4 = col[j + 4];
        const int s5 = col[j + 5];
        const int s6 = col[j + 6];
        const int s7 = col[j + 7];
        const float n0 = dinv[s0] * dd;
        const float n1 = dinv[s1] * dd;
        const float n2 = dinv[s2] * dd;
        const float n3 = dinv[s3] * dd;
        const float n4 = dinv[s4] * dd;
        const float n5 = dinv[s5] * dd;
        const float n6 = dinv[s6] * dd;
        const float n7 = dinv[s7] * dd;
        const float2 v0 = __half22float2(*(const __half2*)&xh[(size_t)s0 * 128 + lane * 2]);
        const float2 v1 = __half22float2(*(const __half2*)&xh[(size_t)s1 * 128 + lane * 2]);
        const float2 v2 = __half22float2(*(const __half2*)&xh[(size_t)s2 * 128 + lane * 2]);
        const float2 v3 = __half22float2(*(const __half2*)&xh[(size_t)s3 * 128 + lane * 2]);
        const float2 v4 = __half22float2(*(const __half2*)&xh[(size_t)s4 * 128 + lane * 2]);
        const float2 v5 = __half22float2(*(const __half2*)&xh[(size_t)s5 * 128 + lane * 2]);
        const float2 v6 = __half22float2(*(const __half2*)&xh[(size_t)s6 * 128 + lane * 2]);
        const float2 v7 = __half22float2(*(const __half2*)&xh[(size_t)s7 * 128 + lane * 2]);
        a0.x = fmaf(v0.x, n0, a0.x);
        a0.y = fmaf(v0.y, n0, a0.y);
        a1.x = fmaf(v1.x, n1, a1.x);
        a1.y = fmaf(v1.y, n1, a1.y);
        a2.x = fmaf(v2.x, n2, a2.x);
        a2.y = fmaf(v2.y, n2, a2.y);
        a3.x = fmaf(v3.x, n3, a3.x);
        a3.y = fmaf(v3.y, n3, a3.y);
        a0.x = fmaf(v4.x, n4, a0.x);
        a0.y = fmaf(v4.y, n4, a0.y);
        a1.x = fmaf(v5.x, n5, a1.x);
        a1.y = fmaf(v5.y, n5, a1.y);
        a2.x = fmaf(v6.x, n6, a2.x);
        a2.y = fmaf(v6.y, n6, a2.y);
        a3.x = fmaf(v7.x, n7, a3.x);
        a3.y = fmaf(v7.y, n7, a3.y);
    }
    for (; j < je; ++j) {
        const int s = col[j];
        const float nrm = dinv[s] * dd;
        const float2 v = __half22float2(*(const __half2*)&xh[(size_t)s * 128 + lane * 2]);
        a0.x = fmaf(v.x, nrm, a0.x);
        a0.y = fmaf(v.y, nrm, a0.y);
    }
    const float fx = (a0.x + a1.x) + (a2.x + a3.x);
    const float fy = (a0.y + a1.y) + (a2.y + a3.y);
    *(__half2*)&z1h[selfoff] = __floats2half2_rn(fx, fy);
}

// ---------------- fused_gemm: h2h = (half)(relu(z1@W1+b1) @ W2), fp16 dot2 ----------------
// 512 thr, 64-row block. LDS: Wu (k-pair-packed; W1p 32KB / W2p 16KB time-shared)
// + xlh[64][136] fp16 17KB = 50176B -> 3 blocks/CU. fp32 accumulation via dot2.

__global__ __launch_bounds__(512) void fused_gemm_kernel(
    const __half* __restrict__ z1h, const float* __restrict__ W1,
    const float* __restrict__ b1, const float* __restrict__ W2,
    __half* __restrict__ h2h, int n)
{
    __shared__ __align__(16) h2v Wu[64 * 128];          // 32 KB: W1p then W2p
    __shared__ __align__(16) _Float16 xlh[64][XLH_LD];  // 17 KB
    const int tid = threadIdx.x;

    const int colg = tid & 31;        // phase B: 32 col groups x 4 = 128 cols
    const int j0   = colg * 4;
    const int r0   = (tid >> 5) * 4;  // 16 row groups x 4 = 64 rows

    const float4 bbv = *(const float4*)&b1[j0];  // bias for this thread's cols (L2-hot)

    // ---- phase A: stage W1 -> k-pair-packed fp16; 64 z1h rows ----
    {
        const float4* W4 = (const float4*)W1;   // W1[k][col], 32 float4 per k-row
        #pragma unroll
        for (int i = 0; i < 4; ++i) {
            const int idx = tid + i * 512;      // [0,2048): kp = idx>>5, c4 = idx&31
            const int kp = idx >> 5;
            const int c4 = idx & 31;
            const float4 f0 = W4[(2 * kp) * 32 + c4];
            const float4 f1 = W4[(2 * kp + 1) * 32 + c4];
            WU4 w;
            w.h[0] = h2v{(_Float16)f0.x, (_Float16)f1.x};
            w.h[1] = h2v{(_Float16)f0.y, (_Float16)f1.y};
            w.h[2] = h2v{(_Float16)f0.z, (_Float16)f1.z};
            w.h[3] = h2v{(_Float16)f0.w, (_Float16)f1.w};
            *(uint4*)&Wu[kp * 128 + c4 * 4] = w.u;
        }
    }
    const int row0 = blockIdx.x * 64;
    #pragma unroll
    for (int t = 0; t < 2; ++t) {
        const int idx = tid + t * 512;          // [0,1024): rr = idx>>4, c8 = idx&15
        const int rr = idx >> 4;
        const int c8 = idx & 15;
        const int grow = row0 + rr;
        float4 v = make_float4(0.f, 0.f, 0.f, 0.f);
        if (grow < n) v = *(const float4*)&z1h[(size_t)grow * 128 + c8 * 8];
        *(float4*)&xlh[rr][c8 * 8] = v;         // 8 halfs, 16B aligned (stride 272B)
    }
    __syncthreads();

    // ---- phase B: x1 = relu(z1 @ W1 + b1), 4 rows x 4 cols / thread, dot2 over k-pairs ----
    float c00 = 0.f, c01 = 0.f, c02 = 0.f, c03 = 0.f;
    float c10 = 0.f, c11 = 0.f, c12 = 0.f, c13 = 0.f;
    float c20 = 0.f, c21 = 0.f, c22 = 0.f, c23 = 0.f;
    float c30 = 0.f, c31 = 0.f, c32 = 0.f, c33 = 0.f;
    #pragma unroll 8
    for (int kp = 0; kp < 64; ++kp) {
        WU4 w; w.u = *(const uint4*)&Wu[kp * 128 + j0];
        const h2v x0 = *(const h2v*)&xlh[r0 + 0][kp * 2];
        const h2v x1 = *(const h2v*)&xlh[r0 + 1][kp * 2];
        const h2v x2 = *(const h2v*)&xlh[r0 + 2][kp * 2];
        const h2v x3 = *(const h2v*)&xlh[r0 + 3][kp * 2];
        c00 = fdot2(x0, w.h[0], c00); c01 = fdot2(x0, w.h[1], c01);
        c02 = fdot2(x0, w.h[2], c02); c03 = fdot2(x0, w.h[3], c03);
        c10 = fdot2(x1, w.h[0], c10); c11 = fdot2(x1, w.h[1], c11);
        c12 = fdot2(x1, w.h[2], c12); c13 = fdot2(x1, w.h[3], c13);
        c20 = fdot2(x2, w.h[0], c20); c21 = fdot2(x2, w.h[1], c21);
        c22 = fdot2(x2, w.h[2], c22); c23 = fdot2(x2, w.h[3], c23);
        c30 = fdot2(x3, w.h[0], c30); c31 = fdot2(x3, w.h[1], c31);
        c32 = fdot2(x3, w.h[2], c32); c33 = fdot2(x3, w.h[3], c33);
    }
    __syncthreads();   // phase-B reads of xlh AND Wu complete before overwrite

    // ---- phase C: write x1 (fp16) into xlh; stage W2 -> k-pair-packed fp16 into Wu ----
    {
        HO4 o0, o1, o2, o3;
        o0.h[0] = (_Float16)fmaxf(c00 + bbv.x, 0.f);
        o0.h[1] = (_Float16)fmaxf(c01 + bbv.y, 0.f);
        o0.h[2] = (_Float16)fmaxf(c02 + bbv.z, 0.f);
        o0.h[3] = (_Float16)fmaxf(c03 + bbv.w, 0.f);
        o1.h[0] = (_Float16)fmaxf(c10 + bbv.x, 0.f);
        o1.h[1] = (_Float16)fmaxf(c11 + bbv.y, 0.f);
        o1.h[2] = (_Float16)fmaxf(c12 + bbv.z, 0.f);
        o1.h[3] = (_Float16)fmaxf(c13 + bbv.w, 0.f);
        o2.h[0] = (_Float16)fmaxf(c20 + bbv.x, 0.f);
        o2.h[1] = (_Float16)fmaxf(c21 + bbv.y, 0.f);
        o2.h[2] = (_Float16)fmaxf(c22 + bbv.z, 0.f);
        o2.h[3] = (_Float16)fmaxf(c23 + bbv.w, 0.f);
        o3.h[0] = (_Float16)fmaxf(c30 + bbv.x, 0.f);
        o3.h[1] = (_Float16)fmaxf(c31 + bbv.y, 0.f);
        o3.h[2] = (_Float16)fmaxf(c32 + bbv.z, 0.f);
        o3.h[3] = (_Float16)fmaxf(c33 + bbv.w, 0.f);
        *(uint2*)&xlh[r0 + 0][j0] = o0.u;   // 8B writes, row stride 272B
        *(uint2*)&xlh[r0 + 1][j0] = o1.u;
        *(uint2*)&xlh[r0 + 2][j0] = o2.u;
        *(uint2*)&xlh[r0 + 3][j0] = o3.u;
    }
    {
        const float4* W4 = (const float4*)W2;   // W2[k][col], 16 float4 per k-row
        #pragma unroll
        for (int i = 0; i < 2; ++i) {
            const int idx = tid + i * 512;      // [0,1024): kp = idx>>4, c4 = idx&15
            const int kp = idx >> 4;
            const int c4 = idx & 15;
            const float4 f0 = W4[(2 * kp) * 16 + c4];
            const float4 f1 = W4[(2 * kp + 1) * 16 + c4];
            WU4 w;
            w.h[0] = h2v{(_Float16)f0.x, (_Float16)f1.x};
            w.h[1] = h2v{(_Float16)f0.y, (_Float16)f1.y};
            w.h[2] = h2v{(_Float16)f0.z, (_Float16)f1.z};
            w.h[3] = h2v{(_Float16)f0.w, (_Float16)f1.w};
            *(uint4*)&Wu[kp * 64 + c4 * 4] = w.u;
        }
    }
    __syncthreads();

    // ---- phase D: h2 = x1 @ W2, 2 rows x 4 cols / thread, dot2 over k-pairs ----
    const int colg2 = tid & 15;        // 16 col groups x 4 = 64 cols
    const int j2    = colg2 * 4;
    const int r2    = (tid >> 4) * 2;  // 32 row groups x 2 = 64 rows

    float d00 = 0.f, d01 = 0.f, d02 = 0.f, d03 = 0.f;
    float d10 = 0.f, d11 = 0.f, d12 = 0.f, d13 = 0.f;
    #pragma unroll 8
    for (int kp = 0; kp < 64; ++kp) {
        WU4 w; w.u = *(const uint4*)&Wu[kp * 64 + j2];
        const h2v x0 = *(const h2v*)&xlh[r2 + 0][kp * 2];
        const h2v x1 = *(const h2v*)&xlh[r2 + 1][kp * 2];
        d00 = fdot2(x0, w.h[0], d00); d01 = fdot2(x0, w.h[1], d01);
        d02 = fdot2(x0, w.h[2], d02); d03 = fdot2(x0, w.h[3], d03);
        d10 = fdot2(x1, w.h[0], d10); d11 = fdot2(x1, w.h[1], d11);
        d12 = fdot2(x1, w.h[2], d12); d13 = fdot2(x1, w.h[3], d13);
    }
    const int g0 = row0 + r2;
    if (g0 + 0 < n) {
        union { __half2 h[2]; float2 f; } u;
        u.h[0] = __floats2half2_rn(d00, d01);
        u.h[1] = __floats2half2_rn(d02, d03);
        *(float2*)&h2h[(size_t)(g0 + 0) * 64 + j2] = u.f;
    }
    if (g0 + 1 < n) {
        union { __half2 h[2]; float2 f; } u;
        u.h[0] = __floats2half2_rn(d10, d11);
        u.h[1] = __floats2half2_rn(d12, d13);
        *(float2*)&h2h[(size_t)(g0 + 1) * 64 + j2] = u.f;
    }
}

// ---------------- gather2 + bias + softmax ----------------

__global__ __launch_bounds__(256) void gather2_softmax_kernel(
    const __half* __restrict__ h2h, const int* __restrict__ rowptr,
    const int* __restrict__ col, const float* __restrict__ dinv,
    const float* __restrict__ b2, float* __restrict__ out, int n)
{
    const int wid = blockIdx.x * 4 + (threadIdx.x >> 6);
    if (wid >= n) return;
    const int lane = threadIdx.x & 63;
    const float bias = b2[lane];
    const float dd = dinv[wid];
    float a0 = __half2float(h2h[(size_t)wid * 64 + lane]) * dd * dd;
    float a1 = 0.f, a2 = 0.f, a3 = 0.f;
    const int jb = rowptr[wid];
    const int je = rowptr[wid + 1];
    int j = jb;
    for (; j + 7 < je; j += 8) {
        const int s0 = col[j + 0];
        const int s1 = col[j + 1];
        const int s2 = col[j + 2];
        const int s3 = col[j + 3];
        const int s4 = col[j + 4];
        const int s5 = col[j + 5];
        const int s6 = col[j + 6];
        const int s7 = col[j + 7];
        const float n0 = dinv[s0] * dd;
        const float n1 = dinv[s1] * dd;
        const float n2 = dinv[s2] * dd;
        const float n3 = dinv[s3] * dd;
        const float n4 = dinv[s4] * dd;
        const float n5 = dinv[s5] * dd;
        const float n6 = dinv[s6] * dd;
        const float n7 = dinv[s7] * dd;
        const float v0 = __half2float(h2h[(size_t)s0 * 64 + lane]);
        const float v1 = __half2float(h2h[(size_t)s1 * 64 + lane]);
        const float v2 = __half2float(h2h[(size_t)s2 * 64 + lane]);
        const float v3 = __half2float(h2h[(size_t)s3 * 64 + lane]);
        const float v4 = __half2float(h2h[(size_t)s4 * 64 + lane]);
        const float v5 = __half2float(h2h[(size_t)s5 * 64 + lane]);
        const float v6 = __half2float(h2h[(size_t)s6 * 64 + lane]);
        const float v7 = __half2float(h2h[(size_t)s7 * 64 + lane]);
        a0 = fmaf(v0, n0, a0);
        a1 = fmaf(v1, n1, a1);
        a2 = fmaf(v2, n2, a2);
        a3 = fmaf(v3, n3, a3);
        a0 = fmaf(v4, n4, a0);
        a1 = fmaf(v5, n5, a1);
        a2 = fmaf(v6, n6, a2);
        a3 = fmaf(v7, n7, a3);
    }
    for (; j < je; ++j) {
        const int s = col[j];
        a0 = fmaf(__half2float(h2h[(size_t)s * 64 + lane]), dinv[s] * dd, a0);
    }
    float acc = (a0 + a1) + (a2 + a3);
    acc += bias;

    float m = acc;
    #pragma unroll
    for (int off = 32; off > 0; off >>= 1) m = fmaxf(m, __shfl_xor(m, off));
    const float ev = expf(acc - m);
    float ssum = ev;
    #pragma unroll
    for (int off = 32; off > 0; off >>= 1) ssum += __shfl_xor(ssum, off);
    out[(size_t)wid * 64 + lane] = ev / ssum;
}

// ---------------- launch ----------------

extern "C" void kernel_launch(void* const* d_in, const int* in_sizes, int n_in,
                              void* d_out, int out_size, void* d_ws, size_t ws_size,
                              hipStream_t stream)
{
    const float* x   = (const float*)d_in[0];
    const int*   ei  = (const int*)d_in[1];
    const float* W1  = (const float*)d_in[2];
    const float* b1  = (const float*)d_in[3];
    const float* W2  = (const float*)d_in[4];
    const float* b2  = (const float*)d_in[5];

    const int n = in_sizes[0] / 128;
    const int E = in_sizes[1] / 2;
    const int* src = ei;
    const int* dst = ei + E;

    const int NB       = (n + 127) >> BSHIFT;        // 391 buckets for n=50000 (<= NBMAX)
    const int nblocksE = (E + CHUNK - 1) / CHUNK;    // 196 for E=800000 (<= 256 for scanP)

    // workspace layout (~40 MB)
    float* ws    = (float*)d_ws;
    float* dinv  = ws;                               // n floats (written by fillC)
    __half* z1h  = (__half*)(dinv + n);              // n*128 halfs
    __half* xh   = z1h + (size_t)n * 128;            // n*128 halfs
    __half* h2h  = xh + (size_t)n * 128;             // n*64 halfs
    unsigned int* pairs = (unsigned int*)(h2h + (size_t)n * 64);  // E u32 (packed)
    int* col     = (int*)(pairs + E);                // E
    int* rowptr  = col + E;                          // n+1 (written by fillC)
    int* histT   = rowptr + (n + 1);                 // NB*nblocksE
    int* relOff  = histT + NB * nblocksE;            // NB*nblocksE
    int* btotal  = relOff + NB * nblocksE;           // NB
    int* bucketBase = btotal + NB;                   // NB

    const int B = 256;

    // prep: relu->fp16 staging + chunk bucket histogram (no global atomics)
    const int total8 = n * 16;
    const int nblocksX = (total8 + CHUNK - 1) / CHUNK;
    const int prep_blocks = (nblocksX > nblocksE) ? nblocksX : nblocksE;
    prep_kernel<<<prep_blocks, PREP_T, 0, stream>>>(x, xh, total8, dst,
                                                    histT, E, NB, nblocksE);

    // bucket offsets: per-bucket chunk scan -> bucket-total scan
    scanP_kernel<<<NB, B, 0, stream>>>(histT, relOff, btotal, nblocksE);
    scanBk_kernel<<<1, NBMAX, 0, stream>>>(btotal, bucketBase, NB);

    // bucket-sorted pairs, then per-bucket count/scan/fill (rowptr, dinv, col)
    scatterB_kernel<<<nblocksE, B, 0, stream>>>(src, dst, bucketBase, relOff,
                                                pairs, E, NB, nblocksE);
    fillC_kernel<<<NB, B, 0, stream>>>(pairs, bucketBase, btotal,
                                       rowptr, dinv, col, n, E);

    // layer 1 aggregate (fp16 out), then fused layer-1+2 GEMMs (x1 never leaves LDS)
    const int gather_blocks = (n + 3) / 4;
    gather1_kernel<<<gather_blocks, B, 0, stream>>>(xh, rowptr, col, dinv, z1h, n);

    fused_gemm_kernel<<<(n + 63) / 64, 512, 0, stream>>>(z1h, W1, b1, W2, h2h, n);

    // layer 2 aggregate + bias + softmax fused
    gather2_softmax_kernel<<<gather_blocks, B, 0, stream>>>(h2h, rowptr, col, dinv, b2,
                                                            (float*)d_out, n);
}